// Round 7
// baseline (281.413 us; speedup 1.0000x reference)
//
#include <hip/hip_runtime.h>
#include <math.h>

// Problem constants
constexpr int Dm  = 1024;
constexpr int Hh  = 16;
constexpr int HDm = 64;
constexpr int FFm = 4096;
constexpr int Bb  = 2;
constexpr int Sq  = 2048;
constexpr int Mm  = Bb * Sq;   // 4096 rows

typedef __attribute__((ext_vector_type(8))) short short8;
typedef __attribute__((ext_vector_type(4))) short short4v;
typedef __attribute__((ext_vector_type(4))) float f32x4;

#define AS1 __attribute__((address_space(1)))
#define AS3 __attribute__((address_space(3)))

// log2(e)/64 : folded into Q so scores come out of QK^T ready for exp2
constexpr float QSCALE = 0.022542110013890054f;

__device__ __forceinline__ unsigned short f2b(float f) {
    union { float f; unsigned u; } v; v.f = f;
    unsigned r = v.u + 0x7FFFu + ((v.u >> 16) & 1u);   // RNE
    return (unsigned short)(r >> 16);
}

// ---------------------------------------------------------------------------
// Prep kernels
// ---------------------------------------------------------------------------
__global__ __launch_bounds__(256) void convert_x(const float* __restrict__ x,
                                                 short* __restrict__ xb) {
    int i = blockIdx.x * 256 + threadIdx.x;          // float4 index
    float4 v = ((const float4*)x)[i];
    short4v o;
    o[0] = (short)f2b(v.x); o[1] = (short)f2b(v.y);
    o[2] = (short)f2b(v.z); o[3] = (short)f2b(v.w);
    ((short4v*)xb)[i] = o;
}

// src [R][C] f32 -> dst [C][R] bf16
__global__ __launch_bounds__(256) void transpose_to_bf16(
    const float* __restrict__ src, short* __restrict__ dst, int R, int C) {
    __shared__ float t[64][65];
    const int c0 = blockIdx.x * 64, r0 = blockIdx.y * 64;
    const int lc = threadIdx.x & 63, lr4 = threadIdx.x >> 6;
    #pragma unroll
    for (int p = 0; p < 16; ++p) {
        int rr = p * 4 + lr4;
        t[rr][lc] = src[(size_t)(r0 + rr) * C + c0 + lc];
    }
    __syncthreads();
    #pragma unroll
    for (int p = 0; p < 16; ++p) {
        int rr = p * 4 + lr4;   // row in dst tile (= source col)
        dst[(size_t)(c0 + rr) * R + r0 + lc] = (short)f2b(t[lc][rr]);
    }
}

// Wq/Wk/Wv [H][1024][64] -> wqkvt [3072][1024] bf16 (n = which*1024 + h*64 + e)
__global__ __launch_bounds__(256) void build_wqkv(
    const float* __restrict__ Wq, const float* __restrict__ Wk,
    const float* __restrict__ Wv, short* __restrict__ dst) {
    const int kt = blockIdx.x, h = blockIdx.y, which = blockIdx.z;
    const float* W = ((which == 0) ? Wq : (which == 1) ? Wk : Wv) +
                     (size_t)h * Dm * HDm;
    __shared__ float t[64][65];
    const int lc = threadIdx.x & 63, lr4 = threadIdx.x >> 6;
    #pragma unroll
    for (int p = 0; p < 16; ++p) {
        int kr = p * 4 + lr4;
        t[kr][lc] = W[(size_t)(kt * 64 + kr) * HDm + lc];
    }
    __syncthreads();
    const int nbase = which * 1024 + h * 64;
    #pragma unroll
    for (int p = 0; p < 16; ++p) {
        int e = p * 4 + lr4;
        dst[(size_t)(nbase + e) * Dm + kt * 64 + lc] = (short)f2b(t[lc][e]);
    }
}

__global__ __launch_bounds__(256) void build_bqkv(
    const float* __restrict__ bq, const float* __restrict__ bk,
    const float* __restrict__ bv, float* __restrict__ bcat) {
    int n = blockIdx.x * 256 + threadIdx.x;
    const float* s = (n < 1024) ? bq : (n < 2048) ? bk : bv;
    bcat[n] = s[n & 1023];
}

// V [B,H,S,64] bf16 -> Vt [B,H,64,S] bf16
__global__ __launch_bounds__(256) void transpose_v(
    const short* __restrict__ v, short* __restrict__ vt)
{
    const int st = blockIdx.x;                 // S tile of 64
    const int h = blockIdx.y & 15, b = blockIdx.y >> 4;
    __shared__ short t[64][72];
    const int tid = threadIdx.x;
    const size_t base = ((size_t)b * Hh + h) * Sq * HDm;
    #pragma unroll
    for (int r = 0; r < 2; ++r) {
        int c = tid + 256 * r;
        int srow = c >> 3, sch = c & 7;
        *(short8*)&t[srow][sch * 8] =
            *(const short8*)(v + base + (size_t)(st * 64 + srow) * HDm + sch * 8);
    }
    __syncthreads();
    const size_t obase = ((size_t)b * Hh + h) * HDm * Sq;
    #pragma unroll
    for (int r = 0; r < 2; ++r) {
        int c = tid + 256 * r;
        int erow = c >> 3, sch = c & 7;
        short8 o8;
        #pragma unroll
        for (int j = 0; j < 8; ++j) o8[j] = t[sch * 8 + j][erow];
        *(short8*)(vt + obase + (size_t)erow * Sq + st * 64 + sch * 8) = o8;
    }
}

// ---------------------------------------------------------------------------
// MFMA GEMM (R4-proven form): C[M,N] = A[M,K](bf16) @ Bt[N,K](bf16)^T,
// BMx128 tile, BK=64, 2D grid, 256 thr = 4 waves 2x2.
// ---------------------------------------------------------------------------
template<int EPI, int BM>
__global__ __launch_bounds__(256) void gemm_bf16(
    const short* __restrict__ A, const short* __restrict__ Bt,
    const float* __restrict__ bias, const float* __restrict__ res,
    float* __restrict__ outf, short* __restrict__ outb,
    short* __restrict__ qo, short* __restrict__ ko, short* __restrict__ vo,
    int K, int N)
{
    constexpr int BMW = BM / 2;       // wave M extent
    constexpr int MF  = BMW / 16;     // M fragments per wave
    __shared__ __align__(16) char smem[BM * 128 + 16384];
    char* ldsA = smem;
    char* ldsB = smem + BM * 128;
    const int tid = threadIdx.x;
    const int l = tid & 63, wv = tid >> 6;
    const int wr = wv >> 1, wc = wv & 1, lr = l & 15, lg = l >> 4;
    const int m0 = blockIdx.x * BM, n0 = blockIdx.y * 128;
    const size_t KB = (size_t)K * 2;
    const char* Ab = (const char*)A;
    const char* Bb = (const char*)Bt;

    f32x4 zero4 = {0.f, 0.f, 0.f, 0.f};
    f32x4 acc[MF][4];
    #pragma unroll
    for (int i = 0; i < MF; ++i)
        #pragma unroll
        for (int j = 0; j < 4; ++j) acc[i][j] = zero4;

    for (int k0 = 0; k0 < K; k0 += 64) {
        __syncthreads();
        #pragma unroll
        for (int r = 0; r < BM / 32; ++r) {          // A: BM*8 chunks
            int c  = (wv * (BM / 32) + r) * 64;
            int cl = c + l;
            int row = cl >> 3, j = cl & 7;
            int sw = ((j ^ (row & 7)) << 4);
            __builtin_amdgcn_global_load_lds(
                (const AS1 void*)(Ab + (size_t)(m0 + row) * KB + (size_t)k0 * 2 + sw),
                (AS3 void*)(ldsA + c * 16), 16, 0, 0);
        }
        #pragma unroll
        for (int r = 0; r < 4; ++r) {                // B: 1024 chunks
            int c  = (wv * 4 + r) * 64;
            int cl = c + l;
            int row = cl >> 3, j = cl & 7;
            int sw = ((j ^ (row & 7)) << 4);
            __builtin_amdgcn_global_load_lds(
                (const AS1 void*)(Bb + (size_t)(n0 + row) * KB + (size_t)k0 * 2 + sw),
                (AS3 void*)(ldsB + c * 16), 16, 0, 0);
        }
        __syncthreads();
        #pragma unroll
        for (int ks = 0; ks < 2; ++ks) {
            short8 af[MF], bf[4];
            #pragma unroll
            for (int i = 0; i < MF; ++i) {
                int rowA = wr * BMW + i * 16 + lr;
                af[i] = *(const short8*)(ldsA + rowA * 128 +
                            (((ks * 4 + lg) ^ (rowA & 7)) << 4));
            }
            #pragma unroll
            for (int i = 0; i < 4; ++i) {
                int rowB = wc * 64 + i * 16 + lr;
                bf[i] = *(const short8*)(ldsB + rowB * 128 +
                            (((ks * 4 + lg) ^ (rowB & 7)) << 4));
            }
            #pragma unroll
            for (int i = 0; i < MF; ++i)
                #pragma unroll
                for (int jn = 0; jn < 4; ++jn)
                    acc[i][jn] = __builtin_amdgcn_mfma_f32_16x16x32_bf16(
                        af[i], bf[jn], acc[i][jn], 0, 0, 0);
        }
    }

    // epilogue: C frag (i,jn): row m = (lg*4+r), col n = lr
    #pragma unroll
    for (int i = 0; i < MF; ++i) {
        #pragma unroll
        for (int jn = 0; jn < 4; ++jn) {
            #pragma unroll
            for (int r = 0; r < 4; ++r) {
                int m = m0 + wr * BMW + i * 16 + lg * 4 + r;
                int n = n0 + wc * 64 + jn * 16 + lr;
                float val = acc[i][jn][r];
                if (EPI == 0) {
                    val += bias[n] + res[(size_t)m * N + n];
                    outf[(size_t)m * N + n] = val;
                } else if (EPI == 1) {
                    val += bias[n];
                    val = 0.5f * val * (1.0f + erff(val * 0.70710678118654752f));
                    outb[(size_t)m * N + n] = (short)f2b(val);
                } else {
                    val += bias[n];
                    int which = n >> 10, hh = (n >> 6) & 15, e = n & 63;
                    if (which == 0) val *= QSCALE;   // pre-scale Q for attention
                    int bb2 = m >> 11, ss = m & 2047;
                    short* o = (which == 0) ? qo : (which == 1) ? ko : vo;
                    o[(((size_t)bb2 * Hh + hh) * Sq + ss) * HDm + e] = (short)f2b(val);
                }
            }
        }
    }
}

// ---------------------------------------------------------------------------
// MFMA flash attention v6 = v5 compute + two structural changes:
//  - single-barrier double-buffered K/V pipeline:
//      per tile: vmcnt(0) -> barrier -> issue stage(t+1 -> buf^1) -> compute
//    (tile-t loads drain after a full compute phase; one barrier per tile)
//  - triangle pairing: block handles qt=pr and qt=31-pr sequentially ->
//    every block exactly 33 tiles, grid 512, perfectly uniform work.
// LDS 40KB -> 4 blocks/CU capacity; grid 512 = 2 blocks/CU resident.
// ---------------------------------------------------------------------------
__global__ __launch_bounds__(256) void attn_mfma(
    const short* __restrict__ qg, const short* __restrict__ kg,
    const short* __restrict__ vtg, short* __restrict__ ctx)
{
    const int bid = blockIdx.x;
    const int pr = bid >> 5;                      // 0..15 pair index
    const int hb = bid & 31;
    const int h = hb & 15, b = hb >> 4;
    const int tid = threadIdx.x;
    const int l = tid & 63, wv = tid >> 6;
    const int lr = l & 15, lg = l >> 4;

    __shared__ __align__(16) char KlB[2][8192];   // 64 rows x 128B, swizzled
    __shared__ __align__(16) char VtB[2][8192];   // 64 d-rows x 128B, swizzled
    __shared__ __align__(16) char PlB[4][2048];   // per wave 16 rows x 128B, swz

    const size_t bh = ((size_t)b * Hh + h) * Sq;
    const size_t vbase = ((size_t)b * Hh + h) * HDm * Sq;
    char* plw = PlB[wv];

    f32x4 zero4 = {0.f, 0.f, 0.f, 0.f};
    short8 vone;
    #pragma unroll
    for (int j = 0; j < 8; ++j) vone[j] = (short)0x3F80;   // bf16 1.0

    for (int seg = 0; seg < 2; ++seg) {
        const int qt = seg ? (31 - pr) : pr;
        const int qbase = qt * 64 + wv * 16;

        short8 aq[2];
        #pragma unroll
        for (int ks = 0; ks < 2; ++ks)
            aq[ks] = *(const short8*)(qg + (bh + qbase + lr) * HDm + ks * 32 + lg * 8);

        f32x4 oacc[4], lacc = zero4;
        #pragma unroll
        for (int i = 0; i < 4; ++i) oacc[i] = zero4;
        float mreg[4];
        #pragma unroll
        for (int r = 0; r < 4; ++r) mreg[r] = -3e38f;

        // staging sources (pre-swizzled): chunk cl -> row cl>>3, j cl&7
        const char* sK[2]; const char* sV[2];
        #pragma unroll
        for (int r2 = 0; r2 < 2; ++r2) {
            int cl = tid + 256 * r2;
            int row = cl >> 3, j = cl & 7;
            sK[r2] = (const char*)kg + ((bh + row) * HDm + ((j ^ (row & 7)) * 8)) * 2;
            sV[r2] = (const char*)vtg + (vbase + (size_t)row * Sq + ((j ^ (row & 7)) * 8)) * 2;
        }

        __syncthreads();   // all waves done reading buffers (prev segment)
        #pragma unroll
        for (int r2 = 0; r2 < 2; ++r2) {           // stage tile 0 -> buf0
            int c = tid + 256 * r2;
            __builtin_amdgcn_global_load_lds((const AS1 void*)sK[r2],
                (AS3 void*)(KlB[0] + c * 16), 16, 0, 0);
            sK[r2] += 64 * HDm * 2;
            __builtin_amdgcn_global_load_lds((const AS1 void*)sV[r2],
                (AS3 void*)(VtB[0] + c * 16), 16, 0, 0);
            sV[r2] += 64 * 2;
        }

        const int nt = qt + 1;
        for (int tk = 0; tk < nt; ++tk) {
            asm volatile("s_waitcnt vmcnt(0)" ::: "memory");   // tile-tk landed
            __syncthreads();                                   // all waves: data ready, prev compute done
            const int cur = tk & 1;
            if (tk + 1 < nt) {                    // issue next tile into other buf
                #pragma unroll
                for (int r2 = 0; r2 < 2; ++r2) {
                    int c = tid + 256 * r2;
                    __builtin_amdgcn_global_load_lds((const AS1 void*)sK[r2],
                        (AS3 void*)(KlB[cur ^ 1] + c * 16), 16, 0, 0);
                    sK[r2] += 64 * HDm * 2;
                    __builtin_amdgcn_global_load_lds((const AS1 void*)sV[r2],
                        (AS3 void*)(VtB[cur ^ 1] + c * 16), 16, 0, 0);
                    sV[r2] += 64 * 2;
                }
            }
            const char* Kb = KlB[cur];
            const char* Vb = VtB[cur];

            // QK^T: S[16 q][64 key]  (Q pre-scaled -> exp2 domain)
            f32x4 sc[4];
            #pragma unroll
            for (int i = 0; i < 4; ++i) sc[i] = zero4;
            __builtin_amdgcn_s_setprio(1);
            #pragma unroll
            for (int kd = 0; kd < 2; ++kd) {
                #pragma unroll
                for (int nf = 0; nf < 4; ++nf) {
                    short8 bk = *(const short8*)(Kb + (nf * 16 + lr) * 128 +
                                    (((kd * 4 + lg) ^ (lr & 7)) << 4));
                    sc[nf] = __builtin_amdgcn_mfma_f32_16x16x32_bf16(
                        aq[kd], bk, sc[nf], 0, 0, 0);
                }
            }
            __builtin_amdgcn_s_setprio(0);

            // mask (diagonal tile only) + row max
            const bool dm = (tk == qt);
            float mrow[4];
            #pragma unroll
            for (int r = 0; r < 4; ++r) {
                const int qglob = qbase + lg * 4 + r;
                if (dm) {
                    #pragma unroll
                    for (int nf = 0; nf < 4; ++nf)
                        if (tk * 64 + nf * 16 + lr > qglob) sc[nf][r] = -3e38f;
                }
                float mr = fmaxf(fmaxf(sc[0][r], sc[1][r]), fmaxf(sc[2][r], sc[3][r]));
                #pragma unroll
                for (int o = 1; o < 16; o <<= 1)
                    mr = fmaxf(mr, __shfl_xor(mr, o));
                mrow[r] = mr;
            }

            // defer-max (log2 domain, THR=8 -> P <= 256)
            bool grow = (mrow[0] > mreg[0] + 8.f) || (mrow[1] > mreg[1] + 8.f) ||
                        (mrow[2] > mreg[2] + 8.f) || (mrow[3] > mreg[3] + 8.f);
            if (__any((int)grow)) {
                #pragma unroll
                for (int r = 0; r < 4; ++r) {
                    float mnew = fmaxf(mreg[r], mrow[r]);
                    float cf = exp2f(mreg[r] - mnew);
                    mreg[r] = mnew;
                    const int prow = lg * 4 + r;
                    #pragma unroll
                    for (int nf = 0; nf < 4; ++nf) {
                        float p = exp2f(sc[nf][r] - mnew);
                        *(unsigned short*)(plw + prow * 128 +
                            (((nf * 2 + (lr >> 3)) ^ (prow & 7)) << 4) +
                            ((lr & 7) << 1)) = (unsigned short)(__float_as_uint(p) >> 16);
                    }
                    #pragma unroll
                    for (int nf = 0; nf < 4; ++nf) oacc[nf][r] *= cf;
                    lacc[r] *= cf;
                }
            } else {
                #pragma unroll
                for (int r = 0; r < 4; ++r) {
                    const int prow = lg * 4 + r;
                    #pragma unroll
                    for (int nf = 0; nf < 4; ++nf) {
                        float p = exp2f(sc[nf][r] - mreg[r]);
                        *(unsigned short*)(plw + prow * 128 +
                            (((nf * 2 + (lr >> 3)) ^ (prow & 7)) << 4) +
                            ((lr & 7) << 1)) = (unsigned short)(__float_as_uint(p) >> 16);
                    }
                }
            }

            // P wave-local: order writes before reads without a block barrier
            asm volatile("s_waitcnt lgkmcnt(0)" ::: "memory");
            __builtin_amdgcn_sched_barrier(0);

            // PV: O[16 q][64 d] += P @ V ; l row-sum via ones-fragment MFMA
            __builtin_amdgcn_s_setprio(1);
            #pragma unroll
            for (int ks = 0; ks < 2; ++ks) {
                short8 pa = *(const short8*)(plw + lr * 128 +
                                (((ks * 4 + lg) ^ (lr & 7)) << 4));
                #pragma unroll
                for (int nf = 0; nf < 4; ++nf) {
                    short8 bv8 = *(const short8*)(Vb + (nf * 16 + lr) * 128 +
                                    (((ks * 4 + lg) ^ (lr & 7)) << 4));
                    oacc[nf] = __builtin_amdgcn_mfma_f32_16x16x32_bf16(
                        pa, bv8, oacc[nf], 0, 0, 0);
                }
                lacc = __builtin_amdgcn_mfma_f32_16x16x32_bf16(pa, vone, lacc, 0, 0, 0);
            }
            __builtin_amdgcn_s_setprio(0);
        }

        // normalize + write ctx [B,S,D] bf16
        #pragma unroll
        for (int r = 0; r < 4; ++r) {
            float inv = 1.0f / lacc[r];
            int q = qbase + lg * 4 + r;
            size_t o = ((size_t)b * Sq + q) * Dm + h * HDm;
            #pragma unroll
            for (int nf = 0; nf < 4; ++nf)
                ctx[o + nf * 16 + lr] = (short)f2b(oacc[nf][r] * inv);
        }
    }
}

// ---------------------------------------------------------------------------
// Row LayerNorm: block per row (1024), 256 thr x float4. Optional bf16 copy.
// ---------------------------------------------------------------------------
template<int BF16OUT>
__global__ __launch_bounds__(256) void ln_kernel(
    const float* __restrict__ in, const float* __restrict__ g,
    const float* __restrict__ be, float* __restrict__ outf,
    short* __restrict__ outb)
{
    const int m = blockIdx.x;
    const int tid = threadIdx.x;
    const float4 vl = *(const float4*)&in[(size_t)m * Dm + tid * 4];
    float s  = vl.x + vl.y + vl.z + vl.w;
    float s2 = vl.x * vl.x + vl.y * vl.y + vl.z * vl.z + vl.w * vl.w;
    #pragma unroll
    for (int o = 32; o > 0; o >>= 1) {
        s  += __shfl_down(s, o);
        s2 += __shfl_down(s2, o);
    }
    __shared__ float rs[4], rs2[4];
    const int w = tid >> 6;
    if ((tid & 63) == 0) { rs[w] = s; rs2[w] = s2; }
    __syncthreads();
    s  = rs[0] + rs[1] + rs[2] + rs[3];
    s2 = rs2[0] + rs2[1] + rs2[2] + rs2[3];
    const float mean = s * (1.0f / Dm);
    const float var  = s2 * (1.0f / Dm) - mean * mean;
    const float rstd = rsqrtf(var + 1e-5f);
    const float4 gv = *(const float4*)&g[tid * 4];
    const float4 bv = *(const float4*)&be[tid * 4];
    float4 ov;
    ov.x = (vl.x - mean) * rstd * gv.x + bv.x;
    ov.y = (vl.y - mean) * rstd * gv.y + bv.y;
    ov.z = (vl.z - mean) * rstd * gv.z + bv.z;
    ov.w = (vl.w - mean) * rstd * gv.w + bv.w;
    *(float4*)&outf[(size_t)m * Dm + tid * 4] = ov;
    if (BF16OUT) {
        short4v o4;
        o4[0] = (short)f2b(ov.x); o4[1] = (short)f2b(ov.y);
        o4[2] = (short)f2b(ov.z); o4[3] = (short)f2b(ov.w);
        *(short4v*)&outb[(size_t)m * Dm + tid * 4] = o4;
    }
}

// ---------------------------------------------------------------------------
extern "C" void kernel_launch(void* const* d_in, const int* in_sizes, int n_in,
                              void* d_out, int out_size, void* d_ws, size_t ws_size,
                              hipStream_t stream)
{
    const float* x  = (const float*)d_in[0];
    const float* Wq = (const float*)d_in[1];
    const float* bq = (const float*)d_in[2];
    const float* Wk = (const float*)d_in[3];
    const float* bk = (const float*)d_in[4];
    const float* Wv = (const float*)d_in[5];
    const float* bv = (const float*)d_in[6];
    const float* Wo = (const float*)d_in[7];
    const float* bo = (const float*)d_in[8];
    const float* W1 = (const float*)d_in[9];
    const float* b1 = (const float*)d_in[10];
    const float* W2 = (const float*)d_in[11];
    const float* b2 = (const float*)d_in[12];
    const float* g1 = (const float*)d_in[13];
    const float* be1= (const float*)d_in[14];
    const float* g2 = (const float*)d_in[15];
    const float* be2= (const float*)d_in[16];
    float* out = (float*)d_out;

    char* ws = (char*)d_ws;
    size_t off = 0;
    auto alloc = [&](size_t bytes) {
        char* p = ws + off;
        off += (bytes + 255) & ~(size_t)255;
        return p;
    };
    const size_t MD2 = (size_t)Mm * Dm * 2;          // 8 MB
    short* xb    = (short*)alloc(MD2);
    short* wqkvt = (short*)alloc((size_t)3072 * Dm * 2);
    float* bcat  = (float*)alloc(3072 * 4);
    short* wot   = (short*)alloc((size_t)Dm * Dm * 2);
    short* w1t   = (short*)alloc((size_t)FFm * Dm * 2);
    short* w2t   = (short*)alloc((size_t)Dm * FFm * 2);
    short* qb    = (short*)alloc(MD2);
    short* kb    = (short*)alloc(MD2);
    short* vb    = (short*)alloc(MD2);
    short* ctxb  = (short*)alloc(MD2);
    short* hb    = qb;                                // alias: q/k/v/ctx dead by FF1
    float* y     = (float*)alloc((size_t)Mm * Dm * 4);
    float* x1f   = (float*)alloc((size_t)Mm * Dm * 4);
    short* x1b   = (short*)alloc(MD2);
    float* y2    = y;                                 // alias: y dead after LN1
    short* vtb   = (short*)y;                         // alias: vtb dead before Wo-gemm writes y

    // --- weight/activation prep (bf16, transposed) ---
    convert_x<<<Mm * Dm / 1024, 256, 0, stream>>>(x, xb);
    build_wqkv<<<dim3(16, 16, 3), 256, 0, stream>>>(Wq, Wk, Wv, wqkvt);
    build_bqkv<<<12, 256, 0, stream>>>(bq, bk, bv, bcat);
    transpose_to_bf16<<<dim3(16, 16), 256, 0, stream>>>(Wo, wot, Dm, Dm);
    transpose_to_bf16<<<dim3(64, 16), 256, 0, stream>>>(W1, w1t, Dm, FFm);
    transpose_to_bf16<<<dim3(16, 64), 256, 0, stream>>>(W2, w2t, FFm, Dm);

    // --- decoder layer ---
    gemm_bf16<2, 128><<<dim3(32, 24), 256, 0, stream>>>(
        xb, wqkvt, bcat, nullptr, nullptr, nullptr, qb, kb, vb, Dm, 3072);
    transpose_v<<<dim3(32, 32), 256, 0, stream>>>(vb, vtb);
    attn_mfma<<<512, 256, 0, stream>>>(qb, kb, vtb, ctxb);
    gemm_bf16<0, 64><<<dim3(64, 8), 256, 0, stream>>>(
        ctxb, wot, bo, x, y, nullptr, nullptr, nullptr, nullptr, Dm, Dm);
    ln_kernel<1><<<Mm, 256, 0, stream>>>(y, g1, be1, x1f, x1b);
    gemm_bf16<1, 128><<<dim3(32, 32), 256, 0, stream>>>(
        x1b, w1t, b1, nullptr, nullptr, hb, nullptr, nullptr, nullptr, Dm, FFm);
    gemm_bf16<0, 64><<<dim3(64, 8), 256, 0, stream>>>(
        hb, w2t, b2, x1f, y2, nullptr, nullptr, nullptr, nullptr, FFm, Dm);
    ln_kernel<0><<<Mm, 256, 0, stream>>>(y2, g2, be2, out, nullptr);
}

// Round 8
// 264.710 us; speedup vs baseline: 1.0631x; 1.0631x over previous
//
#include <hip/hip_runtime.h>
#include <math.h>

// Problem constants
constexpr int Dm  = 1024;
constexpr int Hh  = 16;
constexpr int HDm = 64;
constexpr int FFm = 4096;
constexpr int Bb  = 2;
constexpr int Sq  = 2048;
constexpr int Mm  = Bb * Sq;   // 4096 rows

typedef __attribute__((ext_vector_type(8))) short short8;
typedef __attribute__((ext_vector_type(4))) short short4v;
typedef __attribute__((ext_vector_type(4))) float f32x4;

#define AS1 __attribute__((address_space(1)))
#define AS3 __attribute__((address_space(3)))

// log2(e)/64 : folded into Q so scores come out of QK^T ready for exp2
constexpr float QSCALE = 0.022542110013890054f;

__device__ __forceinline__ unsigned short f2b(float f) {
    union { float f; unsigned u; } v; v.f = f;
    unsigned r = v.u + 0x7FFFu + ((v.u >> 16) & 1u);   // RNE
    return (unsigned short)(r >> 16);
}

// ---------------------------------------------------------------------------
// Prep kernels
// ---------------------------------------------------------------------------
__global__ __launch_bounds__(256) void convert_x(const float* __restrict__ x,
                                                 short* __restrict__ xb) {
    int i = blockIdx.x * 256 + threadIdx.x;          // float4 index
    float4 v = ((const float4*)x)[i];
    short4v o;
    o[0] = (short)f2b(v.x); o[1] = (short)f2b(v.y);
    o[2] = (short)f2b(v.z); o[3] = (short)f2b(v.w);
    ((short4v*)xb)[i] = o;
}

// src [R][C] f32 -> dst [C][R] bf16
__global__ __launch_bounds__(256) void transpose_to_bf16(
    const float* __restrict__ src, short* __restrict__ dst, int R, int C) {
    __shared__ float t[64][65];
    const int c0 = blockIdx.x * 64, r0 = blockIdx.y * 64;
    const int lc = threadIdx.x & 63, lr4 = threadIdx.x >> 6;
    #pragma unroll
    for (int p = 0; p < 16; ++p) {
        int rr = p * 4 + lr4;
        t[rr][lc] = src[(size_t)(r0 + rr) * C + c0 + lc];
    }
    __syncthreads();
    #pragma unroll
    for (int p = 0; p < 16; ++p) {
        int rr = p * 4 + lr4;   // row in dst tile (= source col)
        dst[(size_t)(c0 + rr) * R + r0 + lc] = (short)f2b(t[lc][rr]);
    }
}

// Wq/Wk/Wv [H][1024][64] -> wqkvt [3072][1024] bf16 (n = which*1024 + h*64 + e)
__global__ __launch_bounds__(256) void build_wqkv(
    const float* __restrict__ Wq, const float* __restrict__ Wk,
    const float* __restrict__ Wv, short* __restrict__ dst) {
    const int kt = blockIdx.x, h = blockIdx.y, which = blockIdx.z;
    const float* W = ((which == 0) ? Wq : (which == 1) ? Wk : Wv) +
                     (size_t)h * Dm * HDm;
    __shared__ float t[64][65];
    const int lc = threadIdx.x & 63, lr4 = threadIdx.x >> 6;
    #pragma unroll
    for (int p = 0; p < 16; ++p) {
        int kr = p * 4 + lr4;
        t[kr][lc] = W[(size_t)(kt * 64 + kr) * HDm + lc];
    }
    __syncthreads();
    const int nbase = which * 1024 + h * 64;
    #pragma unroll
    for (int p = 0; p < 16; ++p) {
        int e = p * 4 + lr4;
        dst[(size_t)(nbase + e) * Dm + kt * 64 + lc] = (short)f2b(t[lc][e]);
    }
}

__global__ __launch_bounds__(256) void build_bqkv(
    const float* __restrict__ bq, const float* __restrict__ bk,
    const float* __restrict__ bv, float* __restrict__ bcat) {
    int n = blockIdx.x * 256 + threadIdx.x;
    const float* s = (n < 1024) ? bq : (n < 2048) ? bk : bv;
    bcat[n] = s[n & 1023];
}

// V [B,H,S,64] bf16 -> Vt [B,H,64,S] bf16
__global__ __launch_bounds__(256) void transpose_v(
    const short* __restrict__ v, short* __restrict__ vt)
{
    const int st = blockIdx.x;                 // S tile of 64
    const int h = blockIdx.y & 15, b = blockIdx.y >> 4;
    __shared__ short t[64][72];
    const int tid = threadIdx.x;
    const size_t base = ((size_t)b * Hh + h) * Sq * HDm;
    #pragma unroll
    for (int r = 0; r < 2; ++r) {
        int c = tid + 256 * r;
        int srow = c >> 3, sch = c & 7;
        *(short8*)&t[srow][sch * 8] =
            *(const short8*)(v + base + (size_t)(st * 64 + srow) * HDm + sch * 8);
    }
    __syncthreads();
    const size_t obase = ((size_t)b * Hh + h) * HDm * Sq;
    #pragma unroll
    for (int r = 0; r < 2; ++r) {
        int c = tid + 256 * r;
        int erow = c >> 3, sch = c & 7;
        short8 o8;
        #pragma unroll
        for (int j = 0; j < 8; ++j) o8[j] = t[sch * 8 + j][erow];
        *(short8*)(vt + obase + (size_t)erow * Sq + st * 64 + sch * 8) = o8;
    }
}

// ---------------------------------------------------------------------------
// 8-phase 256x256 MFMA GEMM (T2+T3+T4+T5), 512 thr = 8 waves (2M x 4N),
// BK=64, double-buffered 128 KiB LDS, counted vmcnt (never 0 in steady state).
// Wave (wm,wn): output rows mf*32+wm*16 (mf 0..7), cols wn*64+nf*16 (nf 0..3).
// Phase p computes mf {2p,2p+1} -> A-half p>>1 (progressive freeing).
// Stage order per K-tile (into other buf): ph0 B-h0, ph1 B-h1, ph2 A-h0, ph3 A-h1.
// Waits: end-ph1 vmcnt(4) [forces this tile's A-h1]; end-ph3 vmcnt(2)
// [forces next tile's B0,B1,A0; leaves its A-h1 in flight]. Last tile: vmcnt(0).
// EPI 1: outb = bf16(gelu(acc+bias));  EPI 2: qkv scatter (q pre-scaled).
// ---------------------------------------------------------------------------
template<int EPI>
__global__ __launch_bounds__(512, 2) void gemm256(
    const short* __restrict__ A, const short* __restrict__ Bt,
    const float* __restrict__ bias,
    short* __restrict__ outb,
    short* __restrict__ qo, short* __restrict__ ko, short* __restrict__ vo,
    int K, int N, int NMT)
{
    __shared__ __align__(16) char lds[131072];
    char* const ldsA = lds;              // [buf][half] 16KB each
    char* const ldsB = lds + 65536;
    const int tid = threadIdx.x;
    const int l = tid & 63, wv = tid >> 6;
    const int wm = wv >> 2, wn = wv & 3;
    const int lr = l & 15, lg = l >> 4;
    const int bid = blockIdx.x;
    const int m0 = (bid % NMT) * 256;
    const int n0 = (bid / NMT) * 256;
    const size_t KB = (size_t)K * 2;
    const int NT = K >> 6;

    // staging source pointers (pre-swizzled): chunk c = tid + 512*i
    const char* pA[2][2];
    const char* pB[2][2];
    #pragma unroll
    for (int i = 0; i < 2; ++i) {
        int c = tid + 512 * i;
        int rh = c >> 3, j = c & 7;
        int sw = (j ^ (rh & 7)) << 4;
        #pragma unroll
        for (int h = 0; h < 2; ++h) {
            pA[h][i] = (const char*)A + (size_t)(m0 + h * 128 + rh) * KB + sw;
            pB[h][i] = (const char*)Bt + (size_t)(n0 + h * 128 + rh) * KB + sw;
        }
    }
    const int dbase = tid * 16;

    f32x4 acc[8][4];
    f32x4 z4 = {0.f, 0.f, 0.f, 0.f};
    #pragma unroll
    for (int i = 0; i < 8; ++i)
        #pragma unroll
        for (int j = 0; j < 4; ++j) acc[i][j] = z4;

#define STAGE_B(h, nb) do {                                                     \
    char* _b = ldsB + ((nb) * 2 + (h)) * 16384;                                 \
    __builtin_amdgcn_global_load_lds((const AS1 void*)pB[h][0],                 \
        (AS3 void*)(_b + dbase), 16, 0, 0);                                     \
    __builtin_amdgcn_global_load_lds((const AS1 void*)pB[h][1],                 \
        (AS3 void*)(_b + dbase + 8192), 16, 0, 0);                              \
    pB[h][0] += 128; pB[h][1] += 128; } while (0)
#define STAGE_A(h, nb) do {                                                     \
    char* _a = ldsA + ((nb) * 2 + (h)) * 16384;                                 \
    __builtin_amdgcn_global_load_lds((const AS1 void*)pA[h][0],                 \
        (AS3 void*)(_a + dbase), 16, 0, 0);                                     \
    __builtin_amdgcn_global_load_lds((const AS1 void*)pA[h][1],                 \
        (AS3 void*)(_a + dbase + 8192), 16, 0, 0);                              \
    pA[h][0] += 128; pA[h][1] += 128; } while (0)

    // prologue: stage kt=0 (order B0,B1,A0,A1); publish all but A-h1
    STAGE_B(0, 0); STAGE_B(1, 0); STAGE_A(0, 0); STAGE_A(1, 0);
    asm volatile("s_waitcnt vmcnt(2)" ::: "memory");
    __builtin_amdgcn_s_barrier();
    __builtin_amdgcn_sched_barrier(0);

    const int swk0 = ((0 + lg) ^ (lr & 7)) << 4;
    const int swk1 = ((4 + lg) ^ (lr & 7)) << 4;

    for (int kt = 0; kt < NT; ++kt) {
        const int buf = kt & 1, nbuf = buf ^ 1;
        const bool more = (kt + 1 < NT);
        char* const Ah0 = ldsA + (buf * 2) * 16384;
        char* const Ah1 = ldsA + (buf * 2 + 1) * 16384;
        char* const Bh  = ldsB + (buf * 2 + (wn >> 1)) * 16384 + (wn & 1) * 8192;

        short8 bf[4][2];
        #pragma unroll
        for (int nf = 0; nf < 4; ++nf) {
            const char* bb = Bh + (nf * 16 + lr) * 128;
            bf[nf][0] = *(const short8*)(bb + swk0);
            bf[nf][1] = *(const short8*)(bb + swk1);
        }
        short8 af[2][2];

#define LOAD_A(p) do {                                                          \
    _Pragma("unroll")                                                           \
    for (int j2 = 0; j2 < 2; ++j2) {                                            \
        const int mf = 2 * (p) + j2;                                            \
        const char* ab = ((mf >> 2) ? Ah1 : Ah0) +                              \
                         ((mf & 3) * 32 + wm * 16 + lr) * 128;                  \
        af[j2][0] = *(const short8*)(ab + swk0);                                \
        af[j2][1] = *(const short8*)(ab + swk1);                                \
    } } while (0)

#define MFMA8(p) do {                                                           \
    _Pragma("unroll")                                                           \
    for (int j2 = 0; j2 < 2; ++j2)                                              \
        _Pragma("unroll")                                                       \
        for (int nf = 0; nf < 4; ++nf) {                                        \
            acc[2 * (p) + j2][nf] = __builtin_amdgcn_mfma_f32_16x16x32_bf16(    \
                af[j2][0], bf[nf][0], acc[2 * (p) + j2][nf], 0, 0, 0);          \
            acc[2 * (p) + j2][nf] = __builtin_amdgcn_mfma_f32_16x16x32_bf16(    \
                af[j2][1], bf[nf][1], acc[2 * (p) + j2][nf], 0, 0, 0);          \
        } } while (0)

        // ---- phase 0 ----
        LOAD_A(0);
        if (more) STAGE_B(0, nbuf);
        __builtin_amdgcn_s_barrier();
        asm volatile("s_waitcnt lgkmcnt(0)" ::: "memory");
        __builtin_amdgcn_sched_barrier(0);
        __builtin_amdgcn_s_setprio(1);
        MFMA8(0);
        __builtin_amdgcn_s_setprio(0);
        __builtin_amdgcn_s_barrier();
        // ---- phase 1 ----
        LOAD_A(1);
        if (more) STAGE_B(1, nbuf);
        __builtin_amdgcn_s_barrier();
        asm volatile("s_waitcnt lgkmcnt(0)" ::: "memory");
        __builtin_amdgcn_sched_barrier(0);
        __builtin_amdgcn_s_setprio(1);
        MFMA8(1);
        __builtin_amdgcn_s_setprio(0);
        if (more) asm volatile("s_waitcnt vmcnt(4)" ::: "memory");
        else      asm volatile("s_waitcnt vmcnt(0)" ::: "memory");
        __builtin_amdgcn_s_barrier();
        __builtin_amdgcn_sched_barrier(0);
        // ---- phase 2 ----
        LOAD_A(2);
        if (more) STAGE_A(0, nbuf);
        __builtin_amdgcn_s_barrier();
        asm volatile("s_waitcnt lgkmcnt(0)" ::: "memory");
        __builtin_amdgcn_sched_barrier(0);
        __builtin_amdgcn_s_setprio(1);
        MFMA8(2);
        __builtin_amdgcn_s_setprio(0);
        __builtin_amdgcn_s_barrier();
        // ---- phase 3 ----
        LOAD_A(3);
        if (more) STAGE_A(1, nbuf);
        __builtin_amdgcn_s_barrier();
        asm volatile("s_waitcnt lgkmcnt(0)" ::: "memory");
        __builtin_amdgcn_sched_barrier(0);
        __builtin_amdgcn_s_setprio(1);
        MFMA8(3);
        __builtin_amdgcn_s_setprio(0);
        asm volatile("s_waitcnt vmcnt(2)" ::: "memory");
        __builtin_amdgcn_s_barrier();
        __builtin_amdgcn_sched_barrier(0);
#undef LOAD_A
#undef MFMA8
    }

    // epilogue
    #pragma unroll
    for (int mf = 0; mf < 8; ++mf) {
        #pragma unroll
        for (int nf = 0; nf < 4; ++nf) {
            #pragma unroll
            for (int r = 0; r < 4; ++r) {
                int m = m0 + mf * 32 + wm * 16 + lg * 4 + r;
                int n = n0 + wn * 64 + nf * 16 + lr;
                float val = acc[mf][nf][r] + bias[n];
                if (EPI == 1) {
                    val = 0.5f * val * (1.0f + erff(val * 0.70710678118654752f));
                    outb[(size_t)m * N + n] = (short)f2b(val);
                } else {
                    int which = n >> 10, hh = (n >> 6) & 15, e = n & 63;
                    if (which == 0) val *= QSCALE;   // pre-scale Q for attention
                    int bb2 = m >> 11, ss = m & 2047;
                    short* o = (which == 0) ? qo : (which == 1) ? ko : vo;
                    o[(((size_t)bb2 * Hh + hh) * Sq + ss) * HDm + e] = (short)f2b(val);
                }
            }
        }
    }
#undef STAGE_A
#undef STAGE_B
}

// ---------------------------------------------------------------------------
// MFMA GEMM (R4-proven form) for Wo / FF2: BMx128 tile, BK=64, 2D grid.
// EPI 0: outf = acc + bias + res (f32)
// ---------------------------------------------------------------------------
template<int EPI, int BM>
__global__ __launch_bounds__(256) void gemm_bf16(
    const short* __restrict__ A, const short* __restrict__ Bt,
    const float* __restrict__ bias, const float* __restrict__ res,
    float* __restrict__ outf, short* __restrict__ outb,
    int K, int N)
{
    constexpr int BMW = BM / 2;       // wave M extent
    constexpr int MF  = BMW / 16;     // M fragments per wave
    __shared__ __align__(16) char smem[BM * 128 + 16384];
    char* ldsA = smem;
    char* ldsB = smem + BM * 128;
    const int tid = threadIdx.x;
    const int l = tid & 63, wv = tid >> 6;
    const int wr = wv >> 1, wc = wv & 1, lr = l & 15, lg = l >> 4;
    const int m0 = blockIdx.x * BM, n0 = blockIdx.y * 128;
    const size_t KB = (size_t)K * 2;
    const char* Ab = (const char*)A;
    const char* Bb = (const char*)Bt;

    f32x4 zero4 = {0.f, 0.f, 0.f, 0.f};
    f32x4 acc[MF][4];
    #pragma unroll
    for (int i = 0; i < MF; ++i)
        #pragma unroll
        for (int j = 0; j < 4; ++j) acc[i][j] = zero4;

    for (int k0 = 0; k0 < K; k0 += 64) {
        __syncthreads();
        #pragma unroll
        for (int r = 0; r < BM / 32; ++r) {          // A: BM*8 chunks
            int c  = (wv * (BM / 32) + r) * 64;
            int cl = c + l;
            int row = cl >> 3, j = cl & 7;
            int sw = ((j ^ (row & 7)) << 4);
            __builtin_amdgcn_global_load_lds(
                (const AS1 void*)(Ab + (size_t)(m0 + row) * KB + (size_t)k0 * 2 + sw),
                (AS3 void*)(ldsA + c * 16), 16, 0, 0);
        }
        #pragma unroll
        for (int r = 0; r < 4; ++r) {                // B: 1024 chunks
            int c  = (wv * 4 + r) * 64;
            int cl = c + l;
            int row = cl >> 3, j = cl & 7;
            int sw = ((j ^ (row & 7)) << 4);
            __builtin_amdgcn_global_load_lds(
                (const AS1 void*)(Bb + (size_t)(n0 + row) * KB + (size_t)k0 * 2 + sw),
                (AS3 void*)(ldsB + c * 16), 16, 0, 0);
        }
        __syncthreads();
        #pragma unroll
        for (int ks = 0; ks < 2; ++ks) {
            short8 af[MF], bf[4];
            #pragma unroll
            for (int i = 0; i < MF; ++i) {
                int rowA = wr * BMW + i * 16 + lr;
                af[i] = *(const short8*)(ldsA + rowA * 128 +
                            (((ks * 4 + lg) ^ (rowA & 7)) << 4));
            }
            #pragma unroll
            for (int i = 0; i < 4; ++i) {
                int rowB = wc * 64 + i * 16 + lr;
                bf[i] = *(const short8*)(ldsB + rowB * 128 +
                            (((ks * 4 + lg) ^ (rowB & 7)) << 4));
            }
            #pragma unroll
            for (int i = 0; i < MF; ++i)
                #pragma unroll
                for (int jn = 0; jn < 4; ++jn)
                    acc[i][jn] = __builtin_amdgcn_mfma_f32_16x16x32_bf16(
                        af[i], bf[jn], acc[i][jn], 0, 0, 0);
        }
    }

    #pragma unroll
    for (int i = 0; i < MF; ++i) {
        #pragma unroll
        for (int jn = 0; jn < 4; ++jn) {
            #pragma unroll
            for (int r = 0; r < 4; ++r) {
                int m = m0 + wr * BMW + i * 16 + lg * 4 + r;
                int n = n0 + wc * 64 + jn * 16 + lr;
                float val = acc[i][jn][r];
                if (EPI == 0) {
                    val += bias[n] + res[(size_t)m * N + n];
                    outf[(size_t)m * N + n] = val;
                } else {
                    val += bias[n];
                    val = 0.5f * val * (1.0f + erff(val * 0.70710678118654752f));
                    outb[(size_t)m * N + n] = (short)f2b(val);
                }
            }
        }
    }
}

// ---------------------------------------------------------------------------
// MFMA flash attention (R6-proven v5): grid 1024 heavy-first, 256 thr = 4 waves;
// wave owns 16 q-rows; KV tile 64; Q pre-scaled; l via ones-MFMA;
// XOR-swizzled LDS staged by global_load_lds (pre-swizzled source).
// ---------------------------------------------------------------------------
__global__ __launch_bounds__(256) void attn_mfma(
    const short* __restrict__ qg, const short* __restrict__ kg,
    const short* __restrict__ vtg, short* __restrict__ ctx)
{
    const int bid = blockIdx.x;
    const int qt = (Sq / 64 - 1) - (bid >> 5);    // heavy blocks first
    const int hb = bid & 31;
    const int h = hb & 15, b = hb >> 4;
    const int tid = threadIdx.x;
    const int l = tid & 63, wv = tid >> 6;
    const int lr = l & 15, lg = l >> 4;

    __shared__ __align__(16) char KlB[8192];      // 64 rows x 128B, swizzled
    __shared__ __align__(16) char VtB[8192];      // 64 d-rows x 128B, swizzled
    __shared__ __align__(16) char PlB[4][2048];   // per wave 16 rows x 128B, swz

    const size_t bh = ((size_t)b * Hh + h) * Sq;
    const size_t vbase = ((size_t)b * Hh + h) * HDm * Sq;

    const int qbase = qt * 64 + wv * 16;
    short8 aq[2];
    #pragma unroll
    for (int ks = 0; ks < 2; ++ks)
        aq[ks] = *(const short8*)(qg + (bh + qbase + lr) * HDm + ks * 32 + lg * 8);

    f32x4 zero4 = {0.f, 0.f, 0.f, 0.f};
    f32x4 oacc[4], lacc = zero4;
    #pragma unroll
    for (int i = 0; i < 4; ++i) oacc[i] = zero4;
    float mreg[4];
    #pragma unroll
    for (int r = 0; r < 4; ++r) mreg[r] = -3e38f;

    short8 vone;
    #pragma unroll
    for (int j = 0; j < 8; ++j) vone[j] = (short)0x3F80;   // bf16 1.0

    char* plw = PlB[wv];

    const char* srcK[2]; const char* srcV[2];
    #pragma unroll
    for (int r2 = 0; r2 < 2; ++r2) {
        int cl = tid + 256 * r2;
        int row = cl >> 3, j = cl & 7;
        srcK[r2] = (const char*)kg + ((bh + row) * HDm + ((j ^ (row & 7)) * 8)) * 2;
        srcV[r2] = (const char*)vtg + (vbase + (size_t)row * Sq + ((j ^ (row & 7)) * 8)) * 2;
    }

    const int nt = qt + 1;
    for (int tk = 0; tk < nt; ++tk) {
        __syncthreads();
        #pragma unroll
        for (int r2 = 0; r2 < 2; ++r2) {
            int c = tid + 256 * r2;
            __builtin_amdgcn_global_load_lds((const AS1 void*)srcK[r2],
                (AS3 void*)(KlB + c * 16), 16, 0, 0);
            srcK[r2] += 64 * HDm * 2;
            __builtin_amdgcn_global_load_lds((const AS1 void*)srcV[r2],
                (AS3 void*)(VtB + c * 16), 16, 0, 0);
            srcV[r2] += 64 * 2;
        }
        __syncthreads();

        f32x4 sc[4];
        #pragma unroll
        for (int i = 0; i < 4; ++i) sc[i] = zero4;
        __builtin_amdgcn_s_setprio(1);
        #pragma unroll
        for (int kd = 0; kd < 2; ++kd) {
            #pragma unroll
            for (int nf = 0; nf < 4; ++nf) {
                short8 bk = *(const short8*)(KlB + (nf * 16 + lr) * 128 +
                                (((kd * 4 + lg) ^ (lr & 7)) << 4));
                sc[nf] = __builtin_amdgcn_mfma_f32_16x16x32_bf16(
                    aq[kd], bk, sc[nf], 0, 0, 0);
            }
        }
        __builtin_amdgcn_s_setprio(0);

        const bool dm = (tk == qt);
        float mrow[4];
        #pragma unroll
        for (int r = 0; r < 4; ++r) {
            const int qglob = qbase + lg * 4 + r;
            if (dm) {
                #pragma unroll
                for (int nf = 0; nf < 4; ++nf)
                    if (tk * 64 + nf * 16 + lr > qglob) sc[nf][r] = -3e38f;
            }
            float mr = fmaxf(fmaxf(sc[0][r], sc[1][r]), fmaxf(sc[2][r], sc[3][r]));
            #pragma unroll
            for (int o = 1; o < 16; o <<= 1)
                mr = fmaxf(mr, __shfl_xor(mr, o));
            mrow[r] = mr;
        }

        bool grow = (mrow[0] > mreg[0] + 8.f) || (mrow[1] > mreg[1] + 8.f) ||
                    (mrow[2] > mreg[2] + 8.f) || (mrow[3] > mreg[3] + 8.f);
        if (__any((int)grow)) {
            #pragma unroll
            for (int r = 0; r < 4; ++r) {
                float mnew = fmaxf(mreg[r], mrow[r]);
                float cf = exp2f(mreg[r] - mnew);
                mreg[r] = mnew;
                const int prow = lg * 4 + r;
                #pragma unroll
                for (int nf = 0; nf < 4; ++nf) {
                    float p = exp2f(sc[nf][r] - mnew);
                    *(unsigned short*)(plw + prow * 128 +
                        (((nf * 2 + (lr >> 3)) ^ (prow & 7)) << 4) +
                        ((lr & 7) << 1)) = (unsigned short)(__float_as_uint(p) >> 16);
                }
                #pragma unroll
                for (int nf = 0; nf < 4; ++nf) oacc[nf][r] *= cf;
                lacc[r] *= cf;
            }
        } else {
            #pragma unroll
            for (int r = 0; r < 4; ++r) {
                const int prow = lg * 4 + r;
                #pragma unroll
                for (int nf = 0; nf < 4; ++nf) {
                    float p = exp2f(sc[nf][r] - mreg[r]);
                    *(unsigned short*)(plw + prow * 128 +
                        (((nf * 2 + (lr >> 3)) ^ (prow & 7)) << 4) +
                        ((lr & 7) << 1)) = (unsigned short)(__float_as_uint(p) >> 16);
                }
            }
        }

        asm volatile("s_waitcnt lgkmcnt(0)" ::: "memory");
        __builtin_amdgcn_sched_barrier(0);

        __builtin_amdgcn_s_setprio(1);
        #pragma unroll
        for (int ks = 0; ks < 2; ++ks) {
            short8 pa = *(const short8*)(plw + lr * 128 +
                            (((ks * 4 + lg) ^ (lr & 7)) << 4));
            #pragma unroll
            for (int nf = 0; nf < 4; ++nf) {
                short8 bv8 = *(const short8*)(VtB + (nf * 16 + lr) * 128 +
                                (((ks * 4 + lg) ^ (lr & 7)) << 4));
                oacc[nf] = __builtin_amdgcn_mfma_f32_16x16x32_bf16(
                    pa, bv8, oacc[nf], 0, 0, 0);
            }
            lacc = __builtin_amdgcn_mfma_f32_16x16x32_bf16(pa, vone, lacc, 0, 0, 0);
        }
        __builtin_amdgcn_s_setprio(0);
    }

    #pragma unroll
    for (int r = 0; r < 4; ++r) {
        float inv = 1.0f / lacc[r];
        int q = qbase + lg * 4 + r;
        size_t o = ((size_t)b * Sq + q) * Dm + h * HDm;
        #pragma unroll
        for (int nf = 0; nf < 4; ++nf)
            ctx[o + nf * 16 + lr] = (short)f2b(oacc[nf][r] * inv);
    }
}

// ---------------------------------------------------------------------------
// Row LayerNorm: block per row (1024), 256 thr x float4. Optional bf16 copy.
// ---------------------------------------------------------------------------
template<int BF16OUT>
__global__ __launch_bounds__(256) void ln_kernel(
    const float* __restrict__ in, const float* __restrict__ g,
    const float* __restrict__ be, float* __restrict__ outf,
    short* __restrict__ outb)
{
    const int m = blockIdx.x;
    const int tid = threadIdx.x;
    const float4 vl = *(const float4*)&in[(size_t)m * Dm + tid * 4];
    float s  = vl.x + vl.y + vl.z + vl.w;
    float s2 = vl.x * vl.x + vl.y * vl.y + vl.z * vl.z + vl.w * vl.w;
    #pragma unroll
    for (int o = 32; o > 0; o >>= 1) {
        s  += __shfl_down(s, o);
        s2 += __shfl_down(s2, o);
    }
    __shared__ float rs[4], rs2[4];
    const int w = tid >> 6;
    if ((tid & 63) == 0) { rs[w] = s; rs2[w] = s2; }
    __syncthreads();
    s  = rs[0] + rs[1] + rs[2] + rs[3];
    s2 = rs2[0] + rs2[1] + rs2[2] + rs2[3];
    const float mean = s * (1.0f / Dm);
    const float var  = s2 * (1.0f / Dm) - mean * mean;
    const float rstd = rsqrtf(var + 1e-5f);
    const float4 gv = *(const float4*)&g[tid * 4];
    const float4 bv = *(const float4*)&be[tid * 4];
    float4 ov;
    ov.x = (vl.x - mean) * rstd * gv.x + bv.x;
    ov.y = (vl.y - mean) * rstd * gv.y + bv.y;
    ov.z = (vl.z - mean) * rstd * gv.z + bv.z;
    ov.w = (vl.w - mean) * rstd * gv.w + bv.w;
    *(float4*)&outf[(size_t)m * Dm + tid * 4] = ov;
    if (BF16OUT) {
        short4v o4;
        o4[0] = (short)f2b(ov.x); o4[1] = (short)f2b(ov.y);
        o4[2] = (short)f2b(ov.z); o4[3] = (short)f2b(ov.w);
        *(short4v*)&outb[(size_t)m * Dm + tid * 4] = o4;
    }
}

// ---------------------------------------------------------------------------
extern "C" void kernel_launch(void* const* d_in, const int* in_sizes, int n_in,
                              void* d_out, int out_size, void* d_ws, size_t ws_size,
                              hipStream_t stream)
{
    const float* x  = (const float*)d_in[0];
    const float* Wq = (const float*)d_in[1];
    const float* bq = (const float*)d_in[2];
    const float* Wk = (const float*)d_in[3];
    const float* bk = (const float*)d_in[4];
    const float* Wv = (const float*)d_in[5];
    const float* bv = (const float*)d_in[6];
    const float* Wo = (const float*)d_in[7];
    const float* bo = (const float*)d_in[8];
    const float* W1 = (const float*)d_in[9];
    const float* b1 = (const float*)d_in[10];
    const float* W2 = (const float*)d_in[11];
    const float* b2 = (const float*)d_in[12];
    const float* g1 = (const float*)d_in[13];
    const float* be1= (const float*)d_in[14];
    const float* g2 = (const float*)d_in[15];
    const float* be2= (const float*)d_in[16];
    float* out = (float*)d_out;

    char* ws = (char*)d_ws;
    size_t off = 0;
    auto alloc = [&](size_t bytes) {
        char* p = ws + off;
        off += (bytes + 255) & ~(size_t)255;
        return p;
    };
    const size_t MD2 = (size_t)Mm * Dm * 2;          // 8 MB
    short* xb    = (short*)alloc(MD2);
    short* wqkvt = (short*)alloc((size_t)3072 * Dm * 2);
    float* bcat  = (float*)alloc(3072 * 4);
    short* wot   = (short*)alloc((size_t)Dm * Dm * 2);
    short* w1t   = (short*)alloc((size_t)FFm * Dm * 2);
    short* w2t   = (short*)alloc((size_t)Dm * FFm * 2);
    short* qb    = (short*)alloc(MD2);
    short* kb    = (short*)alloc(MD2);
    short* vb    = (short*)alloc(MD2);
    short* ctxb  = (short*)alloc(MD2);
    short* hb    = qb;                                // alias: q/k/v dead by FF1
    float* y     = (float*)alloc((size_t)Mm * Dm * 4);
    float* x1f   = (float*)alloc((size_t)Mm * Dm * 4);
    short* x1b   = (short*)alloc(MD2);
    float* y2    = y;                                 // alias: y dead after LN1
    short* vtb   = (short*)y;                         // alias: dead before Wo-gemm

    // --- weight/activation prep (bf16, transposed) ---
    convert_x<<<Mm * Dm / 1024, 256, 0, stream>>>(x, xb);
    build_wqkv<<<dim3(16, 16, 3), 256, 0, stream>>>(Wq, Wk, Wv, wqkvt);
    build_bqkv<<<12, 256, 0, stream>>>(bq, bk, bv, bcat);
    transpose_to_bf16<<<dim3(16, 16), 256, 0, stream>>>(Wo, wot, Dm, Dm);
    transpose_to_bf16<<<dim3(64, 16), 256, 0, stream>>>(W1, w1t, Dm, FFm);
    transpose_to_bf16<<<dim3(16, 64), 256, 0, stream>>>(W2, w2t, FFm, Dm);

    // --- decoder layer ---
    gemm256<2><<<192, 512, 0, stream>>>(
        xb, wqkvt, bcat, nullptr, qb, kb, vb, Dm, 3072, 16);
    transpose_v<<<dim3(32, 32), 256, 0, stream>>>(vb, vtb);
    attn_mfma<<<1024, 256, 0, stream>>>(qb, kb, vtb, ctxb);
    gemm_bf16<0, 64><<<dim3(64, 8), 256, 0, stream>>>(
        ctxb, wot, bo, x, y, nullptr, Dm, Dm);
    ln_kernel<1><<<Mm, 256, 0, stream>>>(y, g1, be1, x1f, x1b);
    gemm256<1><<<256, 512, 0, stream>>>(
        x1b, w1t, b1, hb, nullptr, nullptr, nullptr, Dm, FFm, 16);
    gemm_bf16<0, 64><<<dim3(64, 8), 256, 0, stream>>>(
        hb, w2t, b2, x1f, y2, nullptr, FFm, Dm);
    ln_kernel<0><<<Mm, 256, 0, stream>>>(y2, g2, be2, out, nullptr);
}